// Round 5
// baseline (562.648 us; speedup 1.0000x reference)
//
#include <hip/hip_runtime.h>

// Problem constants: B=1048576, T=11, F=3, H=11, C=7
#define TT 11
#define FF 3
#define HH 11
#define CC 7
#define TF 33      // T*F
#define BLOCK 256
#define XROW 17    // dwords per batch element in LDS (33 f16 halves + 1 pad)

typedef _Float16 h2 __attribute__((ext_vector_type(2)));

// ---- workspace dword offsets ----
// Per-gate block (34 dwords), j = 0..10:
//  [0..5]   z recurrent f16 pairs (h0,h1)..(h10,0)
//  [6..11]  r recurrent pairs
//  [12..17] h recurrent pairs
//  [18,19]  z input pairs, even-t variant: (k0,k1),(k2,0)
//  [20,21]  z input pairs, odd-t variant:  (0,k0),(k1,k2)
//  [22,23]  r input even   [24,25] r input odd
//  [26,27]  h input even   [28,29] h input odd
//  [30] z bias f32 (in+rec)  [31] r bias f32 (in+rec)
//  [32] h recurrent bias f32 (goes through r)  [33] h input bias f32
#define GB   34
#define WS_G 0
#define WS_D (GB * HH)          // 374: [11][7][6] dense f16 pairs
#define WS_DB (WS_D + TT*CC*6)  // 836: [7] f32 dense bias

__device__ __forceinline__ float fdot2(h2 a, h2 b, float c) {
    return __builtin_amdgcn_fdot2(a, b, c, false);  // v_dot2_f32_f16, fp32 accum
}
__device__ __forceinline__ float fast_sigmoid(float a) {
    float t = __builtin_amdgcn_exp2f(-1.44269504088896340736f * a);
    return __builtin_amdgcn_rcpf(1.0f + t);
}
__device__ __forceinline__ float fast_tanh(float a) {
    float t = __builtin_amdgcn_exp2f(-2.88539008177792681472f * a);
    return fmaf(2.0f, __builtin_amdgcn_rcpf(1.0f + t), -1.0f);
}

__global__ void prep_weights(const float* __restrict__ k,
                             const float* __restrict__ rk,
                             const float* __restrict__ bias,
                             const float* __restrict__ dw,
                             const float* __restrict__ db,
                             float* __restrict__ ws) {
    const int tid = threadIdx.x;
    if (tid < HH) {
        const int j = tid;
        float* g = ws + WS_G + j * GB;
        h2* gp = (h2*)g;
        const int cz = j, cr = HH + j, ch = 2 * HH + j;
        #pragma unroll
        for (int p = 0; p < 6; ++p) {
            const int i0 = 2 * p, i1 = 2 * p + 1;
            h2 vz = {(_Float16)rk[i0 * TF + cz],
                     (_Float16)((i1 < HH) ? rk[i1 * TF + cz] : 0.0f)};
            gp[p] = vz;
            h2 vr = {(_Float16)rk[i0 * TF + cr],
                     (_Float16)((i1 < HH) ? rk[i1 * TF + cr] : 0.0f)};
            gp[6 + p] = vr;
            h2 vh = {(_Float16)rk[i0 * TF + ch],
                     (_Float16)((i1 < HH) ? rk[i1 * TF + ch] : 0.0f)};
            gp[12 + p] = vh;
        }
        const int cols[3] = {cz, cr, ch};
        #pragma unroll
        for (int gidx = 0; gidx < 3; ++gidx) {
            const int c = cols[gidx];
            const _Float16 k0 = (_Float16)k[0 * TF + c];
            const _Float16 k1 = (_Float16)k[1 * TF + c];
            const _Float16 k2 = (_Float16)k[2 * TF + c];
            h2 ev0 = {k0, k1}, ev1 = {k2, (_Float16)0.0f};
            h2 od0 = {(_Float16)0.0f, k0}, od1 = {k1, k2};
            gp[18 + gidx * 4 + 0] = ev0;
            gp[18 + gidx * 4 + 1] = ev1;
            gp[18 + gidx * 4 + 2] = od0;
            gp[18 + gidx * 4 + 3] = od1;
        }
        g[30] = bias[cz] + bias[TF + cz];
        g[31] = bias[cr] + bias[TF + cr];
        g[32] = bias[TF + ch];
        g[33] = bias[ch];
    }
    for (int idx = tid; idx < TT * CC; idx += BLOCK) {
        const int t = idx / CC, c = idx % CC;
        h2* d = (h2*)(ws + WS_D + t * 42 + c * 6);
        #pragma unroll
        for (int p = 0; p < 6; ++p) {
            const int j0 = 2 * p, j1 = 2 * p + 1;
            h2 v = {(_Float16)dw[(t * HH + j0) * CC + c],
                    (_Float16)((j1 < HH) ? dw[(t * HH + j1) * CC + c] : 0.0f)};
            d[p] = v;
        }
    }
    if (tid < CC) ws[WS_DB + tid] = db[tid];
}

// one GRU timestep; ODD = t&1 selects the input-weight pairing variant
template <int ODD>
__device__ __forceinline__ void gru_step(int t, const unsigned int* xrow,
                                         const float* __restrict__ ws,
                                         float hf[HH], h2 hp[6], float lg[CC]) {
    // halves 3t..3t+2 live in dwords (3t)>>1 and (3t)>>1 + 1 of this row
    const int dwi = (3 * t) >> 1;
    const unsigned int u0 = xrow[dwi];
    const unsigned int u1 = xrow[dwi + 1];
    const h2 xp0 = __builtin_bit_cast(h2, u0);  // even: (x0,x1) ; odd: (junk,x0)
    const h2 xp1 = __builtin_bit_cast(h2, u1);  // even: (x2,junk); odd: (x1,x2)
    const int IV = 18 + (ODD ? 2 : 0);          // input-variant base pair index

    #pragma unroll
    for (int j = 0; j < HH; ++j) {
        const float* g = ws + WS_G + j * GB;
        const h2* gp = (const h2*)g;
        float az = g[30];
        float ar = g[31];
        float rh = g[32];
        float xh = g[33];
        #pragma unroll
        for (int p = 0; p < 6; ++p) {
            az = fdot2(hp[p], gp[p], az);
            ar = fdot2(hp[p], gp[6 + p], ar);
            rh = fdot2(hp[p], gp[12 + p], rh);
        }
        az = fdot2(xp0, gp[IV + 0], az);      az = fdot2(xp1, gp[IV + 1], az);
        ar = fdot2(xp0, gp[IV + 4], ar);      ar = fdot2(xp1, gp[IV + 5], ar);
        xh = fdot2(xp0, gp[IV + 8], xh);      xh = fdot2(xp1, gp[IV + 9], xh);
        const float z = fast_sigmoid(az);
        const float r = fast_sigmoid(ar);
        const float hh = fast_tanh(fmaf(r, rh, xh));
        hf[j] = hh + z * (hf[j] - hh);  // z*h + (1-z)*hh
    }
    // repack h -> f16 pairs
    #pragma unroll
    for (int p = 0; p < 5; ++p) {
        h2 v = {(_Float16)hf[2 * p], (_Float16)hf[2 * p + 1]};
        hp[p] = v;
    }
    { h2 v = {(_Float16)hf[10], (_Float16)0.0f}; hp[5] = v; }

    // fused dense: logits += h_t @ dw_t
    const h2* dd = (const h2*)(ws + WS_D + t * 42);
    #pragma unroll
    for (int c = 0; c < CC; ++c) {
        float acc = lg[c];
        #pragma unroll
        for (int p = 0; p < 6; ++p) acc = fdot2(hp[p], dd[c * 6 + p], acc);
        lg[c] = acc;
    }
}

__global__ __launch_bounds__(BLOCK, 8) void gru_main(
    const float* __restrict__ x,   // [B, T*F] f32
    const float* __restrict__ ws,  // packed weights
    float* __restrict__ out)       // [B, C]
{
    __shared__ unsigned int sx[BLOCK * XROW];  // 17408 B -> 8 blocks/CU (wave-slot cap)
    const int tid = threadIdx.x;
    const long long base = (long long)blockIdx.x * BLOCK;

    // ---- coalesced stage of x, f32 -> packed f16 halves (33 per element) ----
    {
        const long long gbase = base * TF;
        unsigned short* sx16 = (unsigned short*)sx;
        #pragma unroll
        for (int i = 0; i < TF; ++i) {
            const int e = tid + i * BLOCK;   // flat idx in block tile (grid exact: no guard)
            const float v = x[gbase + e];
            const int b = e / TF, r = e % TF;  // magic-mul
            sx16[b * (2 * XROW) + r] = __builtin_bit_cast(unsigned short, (_Float16)v);
        }
    }
    __syncthreads();

    const unsigned int* xrow = sx + tid * XROW;

    float hf[HH];
    #pragma unroll
    for (int j = 0; j < HH; ++j) hf[j] = 0.0f;
    h2 hp[6];
    #pragma unroll
    for (int p = 0; p < 6; ++p) { h2 zz = {(_Float16)0.0f, (_Float16)0.0f}; hp[p] = zz; }
    float lg[CC];
    #pragma unroll
    for (int c = 0; c < CC; ++c) lg[c] = ws[WS_DB + c];

    // t-loop: manual unroll-by-2 so parity (input-pairing variant) is static
    #pragma unroll 1
    for (int tb = 0; tb < 5; ++tb) {
        const int t0 = 2 * tb;
        gru_step<0>(t0, xrow, ws, hf, hp, lg);
        gru_step<1>(t0 + 1, xrow, ws, hf, hp, lg);
    }
    gru_step<0>(10, xrow, ws, hf, hp, lg);

    // ---- softmax ----
    float m = lg[0];
    #pragma unroll
    for (int c = 1; c < CC; ++c) m = fmaxf(m, lg[c]);
    float s = 0.0f;
    float e[CC];
    #pragma unroll
    for (int c = 0; c < CC; ++c) {
        e[c] = __builtin_amdgcn_exp2f((lg[c] - m) * 1.44269504088896340736f);
        s += e[c];
    }
    const float inv = __builtin_amdgcn_rcpf(s);

    // ---- direct writeback: 7 contiguous dwords/thread, full line coverage ----
    {
        const long long ob = (base + tid) * (long long)CC;
        #pragma unroll
        for (int c = 0; c < CC; ++c) out[ob + c] = e[c] * inv;
    }
}

extern "C" void kernel_launch(void* const* d_in, const int* in_sizes, int n_in,
                              void* d_out, int out_size, void* d_ws, size_t ws_size,
                              hipStream_t stream) {
    const float* x  = (const float*)d_in[0];
    const float* k  = (const float*)d_in[1];
    const float* rk = (const float*)d_in[2];
    const float* bi = (const float*)d_in[3];
    const float* dw = (const float*)d_in[4];
    const float* db = (const float*)d_in[5];
    float* out = (float*)d_out;
    float* ws  = (float*)d_ws;

    const int Bt = in_sizes[0] / TF;  // 1048576 (multiple of BLOCK)
    prep_weights<<<1, BLOCK, 0, stream>>>(k, rk, bi, dw, db, ws);
    const int grid = Bt / BLOCK;      // 4096
    gru_main<<<grid, BLOCK, 0, stream>>>(x, ws, out);
}

// Round 6
// 560.855 us; speedup vs baseline: 1.0032x; 1.0032x over previous
//
#include <hip/hip_runtime.h>

// Problem constants: B=1048576, T=11, F=3, H=11, C=7
#define TT 11
#define FF 3
#define HH 11
#define CC 7
#define TF 33      // T*F
#define BLOCK 256
#define XROW 17    // dwords per batch element in LDS (33 f16 halves + 1 pad)

typedef _Float16 h2 __attribute__((ext_vector_type(2)));

// ---- workspace dword offsets ----
// Per-gate block (34 dwords), j = 0..10:
//  [0..5]   z recurrent f16 pairs (h0,h1)..(h10,0)
//  [6..11]  r recurrent pairs
//  [12..17] h recurrent pairs
//  [18,19]  z input pairs, even-t variant: (k0,k1),(k2,0)
//  [20,21]  z input pairs, odd-t variant:  (0,k0),(k1,k2)
//  [22,23]  r input even   [24,25] r input odd
//  [26,27]  h input even   [28,29] h input odd
//  [30] z bias f32 (in+rec)  [31] r bias f32 (in+rec)
//  [32] h recurrent bias f32 (goes through r)  [33] h input bias f32
#define GB   34
#define WS_G 0
#define WS_D (GB * HH)          // 374: [11][7][6] dense f16 pairs
#define WS_DB (WS_D + TT*CC*6)  // 836: [7] f32 dense bias

__device__ __forceinline__ float fdot2(h2 a, h2 b, float c) {
    return __builtin_amdgcn_fdot2(a, b, c, false);  // v_dot2_f32_f16, fp32 accum
}
__device__ __forceinline__ float fast_sigmoid(float a) {
    float t = __builtin_amdgcn_exp2f(-1.44269504088896340736f * a);
    return __builtin_amdgcn_rcpf(1.0f + t);
}
__device__ __forceinline__ float fast_tanh(float a) {
    float t = __builtin_amdgcn_exp2f(-2.88539008177792681472f * a);
    return fmaf(2.0f, __builtin_amdgcn_rcpf(1.0f + t), -1.0f);
}

__global__ void prep_weights(const float* __restrict__ k,
                             const float* __restrict__ rk,
                             const float* __restrict__ bias,
                             const float* __restrict__ dw,
                             const float* __restrict__ db,
                             float* __restrict__ ws) {
    const int tid = threadIdx.x;
    if (tid < HH) {
        const int j = tid;
        float* g = ws + WS_G + j * GB;
        h2* gp = (h2*)g;
        const int cz = j, cr = HH + j, ch = 2 * HH + j;
        #pragma unroll
        for (int p = 0; p < 6; ++p) {
            const int i0 = 2 * p, i1 = 2 * p + 1;
            h2 vz = {(_Float16)rk[i0 * TF + cz],
                     (_Float16)((i1 < HH) ? rk[i1 * TF + cz] : 0.0f)};
            gp[p] = vz;
            h2 vr = {(_Float16)rk[i0 * TF + cr],
                     (_Float16)((i1 < HH) ? rk[i1 * TF + cr] : 0.0f)};
            gp[6 + p] = vr;
            h2 vh = {(_Float16)rk[i0 * TF + ch],
                     (_Float16)((i1 < HH) ? rk[i1 * TF + ch] : 0.0f)};
            gp[12 + p] = vh;
        }
        const int cols[3] = {cz, cr, ch};
        #pragma unroll
        for (int gidx = 0; gidx < 3; ++gidx) {
            const int c = cols[gidx];
            const _Float16 k0 = (_Float16)k[0 * TF + c];
            const _Float16 k1 = (_Float16)k[1 * TF + c];
            const _Float16 k2 = (_Float16)k[2 * TF + c];
            h2 ev0 = {k0, k1}, ev1 = {k2, (_Float16)0.0f};
            h2 od0 = {(_Float16)0.0f, k0}, od1 = {k1, k2};
            gp[18 + gidx * 4 + 0] = ev0;
            gp[18 + gidx * 4 + 1] = ev1;
            gp[18 + gidx * 4 + 2] = od0;
            gp[18 + gidx * 4 + 3] = od1;
        }
        g[30] = bias[cz] + bias[TF + cz];
        g[31] = bias[cr] + bias[TF + cr];
        g[32] = bias[TF + ch];
        g[33] = bias[ch];
    }
    for (int idx = tid; idx < TT * CC; idx += BLOCK) {
        const int t = idx / CC, c = idx % CC;
        h2* d = (h2*)(ws + WS_D + t * 42 + c * 6);
        #pragma unroll
        for (int p = 0; p < 6; ++p) {
            const int j0 = 2 * p, j1 = 2 * p + 1;
            h2 v = {(_Float16)dw[(t * HH + j0) * CC + c],
                    (_Float16)((j1 < HH) ? dw[(t * HH + j1) * CC + c] : 0.0f)};
            d[p] = v;
        }
    }
    if (tid < CC) ws[WS_DB + tid] = db[tid];
}

// one GRU timestep; ODD = t&1 selects the input-weight pairing variant
template <int ODD>
__device__ __forceinline__ void gru_step(int t, const unsigned int* xrow,
                                         const float* __restrict__ ws,
                                         float hf[HH], h2 hp[6], float lg[CC]) {
    // halves 3t..3t+2 live in dwords (3t)>>1 and (3t)>>1 + 1 of this row
    const int dwi = (3 * t) >> 1;
    const unsigned int u0 = xrow[dwi];
    const unsigned int u1 = xrow[dwi + 1];
    const h2 xp0 = __builtin_bit_cast(h2, u0);  // even: (x0,x1) ; odd: (junk,x0)
    const h2 xp1 = __builtin_bit_cast(h2, u1);  // even: (x2,junk); odd: (x1,x2)
    const int IV = 18 + (ODD ? 2 : 0);          // input-variant base pair index

    #pragma unroll
    for (int j = 0; j < HH; ++j) {
        const float* g = ws + WS_G + j * GB;
        const h2* gp = (const h2*)g;
        float az = g[30];
        float ar = g[31];
        float rh = g[32];
        float xh = g[33];
        #pragma unroll
        for (int p = 0; p < 6; ++p) {
            az = fdot2(hp[p], gp[p], az);
            ar = fdot2(hp[p], gp[6 + p], ar);
            rh = fdot2(hp[p], gp[12 + p], rh);
        }
        az = fdot2(xp0, gp[IV + 0], az);      az = fdot2(xp1, gp[IV + 1], az);
        ar = fdot2(xp0, gp[IV + 4], ar);      ar = fdot2(xp1, gp[IV + 5], ar);
        xh = fdot2(xp0, gp[IV + 8], xh);      xh = fdot2(xp1, gp[IV + 9], xh);
        const float z = fast_sigmoid(az);
        const float r = fast_sigmoid(ar);
        const float hh = fast_tanh(fmaf(r, rh, xh));
        hf[j] = hh + z * (hf[j] - hh);  // z*h + (1-z)*hh
    }
    // repack h -> f16 pairs
    #pragma unroll
    for (int p = 0; p < 5; ++p) {
        h2 v = {(_Float16)hf[2 * p], (_Float16)hf[2 * p + 1]};
        hp[p] = v;
    }
    { h2 v = {(_Float16)hf[10], (_Float16)0.0f}; hp[5] = v; }

    // fused dense: logits += h_t @ dw_t
    const h2* dd = (const h2*)(ws + WS_D + t * 42);
    #pragma unroll
    for (int c = 0; c < CC; ++c) {
        float acc = lg[c];
        #pragma unroll
        for (int p = 0; p < 6; ++p) acc = fdot2(hp[p], dd[c * 6 + p], acc);
        lg[c] = acc;
    }
}

// launch_bounds(256,4): empirically arg>=6 squeezes the VGPR cap below the
// kernel's natural ~56 regs and forces scratch spills (R5: WRITE 29->177 MB,
// VGPR=32, dur +34%). arg=4 leaves cap at 64+ => no spills; <=64 VGPR still
// permits 8 waves/SIMD, so occupancy is LDS/slot-bound (8 blocks/CU), not hurt.
__global__ __launch_bounds__(BLOCK, 4) void gru_main(
    const float* __restrict__ x,   // [B, T*F] f32
    const float* __restrict__ ws,  // packed weights
    float* __restrict__ out)       // [B, C]
{
    __shared__ unsigned int sx[BLOCK * XROW];  // 17408 B
    const int tid = threadIdx.x;
    const long long base = (long long)blockIdx.x * BLOCK;

    // ---- coalesced stage of x, f32 -> packed f16 halves (33 per element) ----
    {
        const long long gbase = base * TF;
        unsigned short* sx16 = (unsigned short*)sx;
        #pragma unroll
        for (int i = 0; i < TF; ++i) {
            const int e = tid + i * BLOCK;   // flat idx in block tile (grid exact: no guard)
            const float v = x[gbase + e];
            const int b = e / TF, r = e % TF;  // magic-mul
            sx16[b * (2 * XROW) + r] = __builtin_bit_cast(unsigned short, (_Float16)v);
        }
    }
    __syncthreads();

    const unsigned int* xrow = sx + tid * XROW;

    float hf[HH];
    #pragma unroll
    for (int j = 0; j < HH; ++j) hf[j] = 0.0f;
    h2 hp[6];
    #pragma unroll
    for (int p = 0; p < 6; ++p) { h2 zz = {(_Float16)0.0f, (_Float16)0.0f}; hp[p] = zz; }
    float lg[CC];
    #pragma unroll
    for (int c = 0; c < CC; ++c) lg[c] = ws[WS_DB + c];

    // t-loop: manual unroll-by-2 so parity (input-pairing variant) is static
    #pragma unroll 1
    for (int tb = 0; tb < 5; ++tb) {
        const int t0 = 2 * tb;
        gru_step<0>(t0, xrow, ws, hf, hp, lg);
        gru_step<1>(t0 + 1, xrow, ws, hf, hp, lg);
    }
    gru_step<0>(10, xrow, ws, hf, hp, lg);

    // ---- softmax ----
    float m = lg[0];
    #pragma unroll
    for (int c = 1; c < CC; ++c) m = fmaxf(m, lg[c]);
    float s = 0.0f;
    float e[CC];
    #pragma unroll
    for (int c = 0; c < CC; ++c) {
        e[c] = __builtin_amdgcn_exp2f((lg[c] - m) * 1.44269504088896340736f);
        s += e[c];
    }
    const float inv = __builtin_amdgcn_rcpf(s);

    // ---- direct writeback: 7 contiguous dwords/thread, full line coverage ----
    {
        const long long ob = (base + tid) * (long long)CC;
        #pragma unroll
        for (int c = 0; c < CC; ++c) out[ob + c] = e[c] * inv;
    }
}

extern "C" void kernel_launch(void* const* d_in, const int* in_sizes, int n_in,
                              void* d_out, int out_size, void* d_ws, size_t ws_size,
                              hipStream_t stream) {
    const float* x  = (const float*)d_in[0];
    const float* k  = (const float*)d_in[1];
    const float* rk = (const float*)d_in[2];
    const float* bi = (const float*)d_in[3];
    const float* dw = (const float*)d_in[4];
    const float* db = (const float*)d_in[5];
    float* out = (float*)d_out;
    float* ws  = (float*)d_ws;

    const int Bt = in_sizes[0] / TF;  // 1048576 (multiple of BLOCK)
    prep_weights<<<1, BLOCK, 0, stream>>>(k, rk, bi, dw, db, ws);
    const int grid = Bt / BLOCK;      // 4096
    gru_main<<<grid, BLOCK, 0, stream>>>(x, ws, out);
}